// Round 3
// baseline (474.963 us; speedup 1.0000x reference)
//
#include <hip/hip_runtime.h>

// Haar inverse DWT2 (db1), fp32.
// Inputs: A, H, V, D each [8,32,256,256] fp32 (flat 16,777,216 elems).
// Output: [8,32,512,512] fp32 (flat 67,108,864 elems).
// x[2i,2j]   = (A+H+V+D)/2    x[2i,2j+1] = (A+H-V-D)/2
// x[2i+1,2j] = (A-H+V-D)/2    x[2i+1,2j+1] = (A-H-V+D)/2
//
// R3: same as R2 but with native clang vectors (ext_vector_type) so
//     __builtin_nontemporal_store compiles (HIP float4 is a class -> rejected).

typedef float f32x4 __attribute__((ext_vector_type(4)));

#define IN_H 256
#define IN_W 256
#define N_IMG (8 * 32)
#define QUADS_PER_ROW (IN_W / 4)              // 64 = 2^6
#define QUADS_PER_IMG (IN_H * QUADS_PER_ROW)  // 16384 = 2^14
#define TOTAL_QUADS (N_IMG * QUADS_PER_IMG)   // 4,194,304

__global__ __launch_bounds__(256) void idwt2_haar_kernel(
    const float* __restrict__ A, const float* __restrict__ Hc,
    const float* __restrict__ V, const float* __restrict__ D,
    float* __restrict__ out) {
  int q = blockIdx.x * blockDim.x + threadIdx.x;  // global quad index
  if (q >= TOTAL_QUADS) return;

  // quad layout matches flat float4 layout of the inputs
  const f32x4 a = ((const f32x4*)A)[q];
  const f32x4 h = ((const f32x4*)Hc)[q];
  const f32x4 v = ((const f32x4*)V)[q];
  const f32x4 d = ((const f32x4*)D)[q];

  const f32x4 lp = a + h;  // low-pass rows (even output row source)
  const f32x4 lm = a - h;  // odd output row source
  const f32x4 mp = v + d;
  const f32x4 mm = v - d;

  f32x4 e0, e1, o0, o1;
  // pair 0: input cols 4jq, 4jq+1 -> output cols 8jq..8jq+3
  e0.x = 0.5f * (lp.x + mp.x);
  e0.y = 0.5f * (lp.x - mp.x);
  e0.z = 0.5f * (lp.y + mp.y);
  e0.w = 0.5f * (lp.y - mp.y);
  // pair 1: input cols 4jq+2, 4jq+3 -> output cols 8jq+4..8jq+7
  e1.x = 0.5f * (lp.z + mp.z);
  e1.y = 0.5f * (lp.z - mp.z);
  e1.z = 0.5f * (lp.w + mp.w);
  e1.w = 0.5f * (lp.w - mp.w);
  o0.x = 0.5f * (lm.x + mm.x);
  o0.y = 0.5f * (lm.x - mm.x);
  o0.z = 0.5f * (lm.y + mm.y);
  o0.w = 0.5f * (lm.y - mm.y);
  o1.x = 0.5f * (lm.z + mm.z);
  o1.y = 0.5f * (lm.z - mm.z);
  o1.z = 0.5f * (lm.w + mm.w);
  o1.w = 0.5f * (lm.w - mm.w);

  int jq = q & (QUADS_PER_ROW - 1);  // 0..63
  int i = (q >> 6) & (IN_H - 1);     // 0..255
  int img = q >> 14;

  size_t obase =
      ((size_t)img * (2 * IN_H) + 2 * (size_t)i) * (2 * IN_W) + 8 * (size_t)jq;
  f32x4* pe = (f32x4*)(out + obase);             // row 2i
  f32x4* po = (f32x4*)(out + obase + 2 * IN_W);  // row 2i+1
  __builtin_nontemporal_store(e0, pe);
  __builtin_nontemporal_store(e1, pe + 1);
  __builtin_nontemporal_store(o0, po);
  __builtin_nontemporal_store(o1, po + 1);
}

extern "C" void kernel_launch(void* const* d_in, const int* in_sizes, int n_in,
                              void* d_out, int out_size, void* d_ws,
                              size_t ws_size, hipStream_t stream) {
  const float* A = (const float*)d_in[0];
  const float* Hc = (const float*)d_in[1];
  const float* V = (const float*)d_in[2];
  const float* D = (const float*)d_in[3];
  float* out = (float*)d_out;

  const int threads = 256;
  const int blocks = TOTAL_QUADS / threads;  // 16384
  idwt2_haar_kernel<<<blocks, threads, 0, stream>>>(A, Hc, V, D, out);
}